// Round 20
// baseline (250.535 us; speedup 1.0000x reference)
//
#include <hip/hip_runtime.h>
#include <math.h>

#define HIDDEN 2048
#define NHEADS 16
#define HD     128
#define QKV3   6144
#define EPSV   1e-5f
#define NEGBIG -30000.0f

typedef short bf16x8 __attribute__((ext_vector_type(8)));
typedef float f32x4  __attribute__((ext_vector_type(4)));

__device__ inline unsigned short f2bf(float f) {
    unsigned u = __float_as_uint(f);
    u += 0x7fff + ((u >> 16) & 1);          // round-to-nearest-even
    return (unsigned short)(u >> 16);
}
__device__ inline float bf2f(unsigned short h) {
    return __uint_as_float(((unsigned)h) << 16);
}

union FragCast { uint4 u; bf16x8 v; };
__device__ inline bf16x8 as_frag(uint4 x) { FragCast c; c.u = x; return c.v; }
union U16x8 { unsigned short h[8]; uint4 v; };

// async global->LDS, 16B per lane (wave-uniform LDS base, HW linear scatter)
__device__ __forceinline__ void gload16(const void* gsrc, void* ldst) {
    typedef __attribute__((address_space(1))) const char GC;
    typedef __attribute__((address_space(3))) char LC;
    __builtin_amdgcn_global_load_lds((GC*)(unsigned long long)gsrc,
                                     (LC*)(unsigned long long)ldst, 16, 0, 0);
}

// ---------------- fp32 -> bf16 conversion (weights) ----------------
__global__ __launch_bounds__(256) void f32_to_bf16_kernel(
        const float* __restrict__ in, unsigned short* __restrict__ out, int count) {
    int i = (blockIdx.x * 256 + threadIdx.x) * 4;
    if (i >= count) return;
    float4 v = *(const float4*)&in[i];
    ushort4 o = {f2bf(v.x), f2bf(v.y), f2bf(v.z), f2bf(v.w)};
    *(ushort4*)&out[i] = o;
}

// ---------------- RoPE cos/sin table ----------------
__global__ void rope_table_kernel(float* __restrict__ cost, float* __restrict__ sint) {
    int pos = blockIdx.x;
    int i   = threadIdx.x;              // 0..63
    float inv = exp2f((float)i * (-17.1946030f / 64.0f));   // 150000^(-i/64)
    float f   = (float)pos * inv;
    cost[pos * 64 + i] = cosf(f);
    sint[pos * 64 + i] = sinf(f);
}

// ---------------- RMSNorm (fp32 in, bf16 out) ----------------
__global__ __launch_bounds__(256) void rmsnorm_kernel(
        const float* __restrict__ x, const float* __restrict__ scale,
        unsigned short* __restrict__ t) {
    int row = blockIdx.x;
    int tid = threadIdx.x;
    const float* xr = x + (size_t)row * HIDDEN;
    unsigned short* tr = t + (size_t)row * HIDDEN;

    float4 v[2];
    float ss = 0.f;
#pragma unroll
    for (int u = 0; u < 2; ++u) {
        v[u] = ((const float4*)xr)[tid + u * 256];
        ss += v[u].x * v[u].x + v[u].y * v[u].y + v[u].z * v[u].z + v[u].w * v[u].w;
    }
#pragma unroll
    for (int off = 32; off; off >>= 1) ss += __shfl_xor(ss, off);
    __shared__ float wsum[4];
    if ((tid & 63) == 0) wsum[tid >> 6] = ss;
    __syncthreads();
    float tot = wsum[0] + wsum[1] + wsum[2] + wsum[3];
    float r = rsqrtf(tot / (float)HIDDEN + EPSV);
#pragma unroll
    for (int u = 0; u < 2; ++u) {
        int idx = tid + u * 256;
        float4 sc = ((const float4*)scale)[idx];
        ushort4 o = {f2bf(v[u].x * r * sc.x), f2bf(v[u].y * r * sc.y),
                     f2bf(v[u].z * r * sc.z), f2bf(v[u].w * r * sc.w)};
        ((ushort4*)tr)[idx] = o;
    }
}

// ---------------- generic bf16 MFMA NT GEMM (BK=64) ----------------
// 128x128 tile, BK=64: half the barriers of BK=32, 32 MFMAs per K-step,
// 8 global_load_lds in flight per thread per stage. LDS 32 KB.
__global__ __launch_bounds__(256) void gemm_bf16_kernel(
        const unsigned short* __restrict__ A, const unsigned short* __restrict__ B,
        const float* __restrict__ bias, const float* __restrict__ resid,
        float* __restrict__ C, int M, int N, int K) {
    __shared__ __align__(16) unsigned short As[128][64];
    __shared__ __align__(16) unsigned short Bs[128][64];

    int tid  = threadIdx.x;
    int bn   = blockIdx.x * 128;
    int bm   = blockIdx.y * 128;
    int lane = tid & 63;
    int wid  = tid >> 6;
    int wr   = wid >> 1;
    int wc   = wid & 1;
    int fr   = lane & 15;
    int fq   = lane >> 4;

    f32x4 acc[4][4] = {};

    const int nk = K >> 6;
    for (int kt = 0; kt < nk; ++kt) {
        int k0 = kt << 6;
        // stage 128x64 per matrix = 1024 16B chunks; per wave+u: 64 chunks
        // = 8 rows from base As[wid*8 + u*32][0] (linear, wave-uniform base)
#pragma unroll
        for (int u = 0; u < 4; ++u) {
            int c   = tid + u * 256;
            int row = c >> 3;
            int kk  = (c & 7) * 8;
            gload16(&A[(size_t)(bm + row) * K + k0 + kk], &As[(wid << 3) + (u << 5)][0]);
            gload16(&B[(size_t)(bn + row) * K + k0 + kk], &Bs[(wid << 3) + (u << 5)][0]);
        }
        __syncthreads();

#pragma unroll
        for (int ks = 0; ks < 2; ++ks) {
            bf16x8 af[4], bfr[4];
#pragma unroll
            for (int i = 0; i < 4; ++i) {
                af[i]  = as_frag(*(const uint4*)&As[wr * 64 + i * 16 + fr][ks * 32 + fq * 8]);
                bfr[i] = as_frag(*(const uint4*)&Bs[wc * 64 + i * 16 + fr][ks * 32 + fq * 8]);
            }
#pragma unroll
            for (int mi = 0; mi < 4; ++mi)
#pragma unroll
                for (int ni = 0; ni < 4; ++ni)
                    acc[mi][ni] = __builtin_amdgcn_mfma_f32_16x16x32_bf16(
                        af[mi], bfr[ni], acc[mi][ni], 0, 0, 0);
        }
        __syncthreads();
    }

#pragma unroll
    for (int ni = 0; ni < 4; ++ni) {
        int col = bn + wc * 64 + ni * 16 + fr;
        float bb = bias[col];
#pragma unroll
        for (int mi = 0; mi < 4; ++mi) {
#pragma unroll
            for (int r = 0; r < 4; ++r) {
                int row = bm + wr * 64 + mi * 16 + fq * 4 + r;
                float v = acc[mi][ni][r] + bb;
                if (resid) v += resid[(size_t)row * N + col];
                C[(size_t)row * N + col] = v;
            }
        }
    }
}

// ---------------- fused QKV GEMM (BK=64): RoPE + repack + V-transpose -------
// Each col-tile (bn) covers exactly one head's 128 dims of q, k, or v.
// C-tile staged in LDS (union w/ As/Bs), then stored as qb/kb (RoPE) or vt (T).
__global__ __launch_bounds__(256) void gemm_qkv_fused_kernel(
        const unsigned short* __restrict__ A,    // tb [n][2048] bf16
        const unsigned short* __restrict__ B,    // wq [6144][2048] bf16
        const float* __restrict__ bias,          // qkv_b [6144]
        const float* __restrict__ cost, const float* __restrict__ sint,
        unsigned short* __restrict__ qb, unsigned short* __restrict__ kb,
        unsigned short* __restrict__ vt, int n) {
    const int K = HIDDEN;
    __shared__ __align__(16) char smem[33792];   // max(As+Bs 32KB, Ct 33792B)
    auto As = (unsigned short(*)[64])smem;
    auto Bs = (unsigned short(*)[64])(smem + 16384);
    auto Ct = (unsigned short(*)[132])smem;      // [128][132] bf16, +4 pad

    int tid  = threadIdx.x;
    int bn   = blockIdx.x * 128;
    int bm   = blockIdx.y * 128;
    int lane = tid & 63;
    int wid  = tid >> 6;
    int wr   = wid >> 1;
    int wc   = wid & 1;
    int fr   = lane & 15;
    int fq   = lane >> 4;

    f32x4 acc[4][4] = {};

    const int nk = K >> 6;
    for (int kt = 0; kt < nk; ++kt) {
        int k0 = kt << 6;
#pragma unroll
        for (int u = 0; u < 4; ++u) {
            int c   = tid + u * 256;
            int row = c >> 3;
            int kk  = (c & 7) * 8;
            gload16(&A[(size_t)(bm + row) * K + k0 + kk], &As[(wid << 3) + (u << 5)][0]);
            gload16(&B[(size_t)(bn + row) * K + k0 + kk], &Bs[(wid << 3) + (u << 5)][0]);
        }
        __syncthreads();

#pragma unroll
        for (int ks = 0; ks < 2; ++ks) {
            bf16x8 af[4], bfr[4];
#pragma unroll
            for (int i = 0; i < 4; ++i) {
                af[i]  = as_frag(*(const uint4*)&As[wr * 64 + i * 16 + fr][ks * 32 + fq * 8]);
                bfr[i] = as_frag(*(const uint4*)&Bs[wc * 64 + i * 16 + fr][ks * 32 + fq * 8]);
            }
#pragma unroll
            for (int mi = 0; mi < 4; ++mi)
#pragma unroll
                for (int ni = 0; ni < 4; ++ni)
                    acc[mi][ni] = __builtin_amdgcn_mfma_f32_16x16x32_bf16(
                        af[mi], bfr[ni], acc[mi][ni], 0, 0, 0);
        }
        __syncthreads();                          // also frees As/Bs for Ct
    }

    // phase 1: acc (+bias) -> Ct bf16
#pragma unroll
    for (int ni = 0; ni < 4; ++ni) {
        int lc = wc * 64 + ni * 16 + fr;
        float bb = bias[bn + lc];
#pragma unroll
        for (int mi = 0; mi < 4; ++mi)
#pragma unroll
            for (int r = 0; r < 4; ++r)
                Ct[wr * 64 + mi * 16 + fq * 4 + r][lc] = f2bf(acc[mi][ni][r] + bb);
    }
    __syncthreads();

    // phase 2: region store
    int region = bn >> 11;            // 0=q, 1=k, 2=v
    int h      = (bn & 2047) >> 7;    // head
    if (region == 2) {
        // v: vt[(h*128 + d)*n + pos], transpose from Ct[pos_local][d]
#pragma unroll
        for (int u = 0; u < 8; ++u) {
            int c2 = tid + u * 256;               // 0..2047
            int d  = c2 >> 4;                     // 0..127
            int r0 = (c2 & 15) * 8;               // 0..120
            U16x8 o;
#pragma unroll
            for (int e = 0; e < 8; ++e) o.h[e] = Ct[r0 + e][d];
            *(uint4*)&vt[((size_t)h * HD + d) * n + bm + r0] = o.v;
        }
    } else {
        unsigned short* dst = region ? kb : qb;
        float scq = region ? 1.0f : 0.088388347648318447f;   // q: 1/sqrt(128)
#pragma unroll
        for (int u = 0; u < 4; ++u) {
            int t2 = tid + u * 256;               // 0..1023
            int rr = t2 >> 3;                     // 0..127
            int d0 = (t2 & 7) * 8;                // 0..56
            int pos = bm + rr;
            float4 c0 = *(const float4*)&cost[pos * 64 + d0];
            float4 c1 = *(const float4*)&cost[pos * 64 + d0 + 4];
            float4 s0 = *(const float4*)&sint[pos * 64 + d0];
            float4 s1 = *(const float4*)&sint[pos * 64 + d0 + 4];
            float cv[8] = {c0.x, c0.y, c0.z, c0.w, c1.x, c1.y, c1.z, c1.w};
            float sv[8] = {s0.x, s0.y, s0.z, s0.w, s1.x, s1.y, s1.z, s1.w};
            U16x8 lo, hi;
#pragma unroll
            for (int e = 0; e < 8; ++e) {
                float x1 = bf2f(Ct[rr][d0 + e]);
                float x2 = bf2f(Ct[rr][d0 + 64 + e]);
                lo.h[e] = f2bf((x1 * cv[e] - x2 * sv[e]) * scq);
                hi.h[e] = f2bf((x2 * cv[e] + x1 * sv[e]) * scq);
            }
            unsigned short* drow = dst + ((size_t)h * n + pos) * HD;
            *(uint4*)&drow[d0]      = lo.v;
            *(uint4*)&drow[d0 + 64] = hi.v;
        }
    }
}

// ---------------- split-KV MFMA flash attention (partials) ----------------
// 1-D grid (n/128 * NHEADS * NSPLIT), block 512 = 8 waves x 16 q-rows.
// Head->XCD pinning: fid = h + 16*rest => fid%8 == h%8 (2 heads per XCD L2).
#define QB  128
#define KVB 64
#define NSPLIT 4
__global__ __launch_bounds__(512) void attn_part_kernel(
        const unsigned short* __restrict__ qb_,  // [H][n][128] (pre-scaled)
        const unsigned short* __restrict__ kb,   // [H][n][128]
        const unsigned short* __restrict__ vt,   // [H][128][n]
        unsigned short* __restrict__ o_part,     // [S][H][n][128] bf16
        float* __restrict__ m_part,              // [S][H][n]
        float* __restrict__ l_part, int n) {
    int nqb  = n / QB;                           // 16
    int fid  = blockIdx.x;
    int h    = fid & 15;                         // NHEADS-1
    int rest = fid >> 4;                         // 0 .. nqb*NSPLIT-1
    int qbi  = (nqb - 1) - (rest % nqb);         // long q-blocks first
    int s    = rest / nqb;
    int q0   = qbi * QB;
    int ntiles = (q0 + QB) / KVB;                // 2*(qbi+1)
    int chunk  = (ntiles + NSPLIT - 1) >> 2;
    int t0 = s * chunk;
    int t1 = t0 + chunk; if (t1 > ntiles) t1 = ntiles;
    int tid = threadIdx.x;

    if (t0 >= ntiles) {                          // empty split: weight-0 partial
        if (tid < QB) {
            size_t idx = ((size_t)s * NHEADS + h) * n + q0 + tid;
            m_part[idx] = NEGBIG;
            l_part[idx] = 0.f;
            for (int e = 0; e < HD / 8; ++e) {
                U16x8 z; z.v = make_uint4(0, 0, 0, 0);
                *(uint4*)&o_part[idx * HD + e * 8] = z.v;
            }
        }
        return;
    }

    int lane = tid & 63, w = tid >> 6;           // w = 0..7
    int g = lane >> 4, i = lane & 15;
    int myrow0 = q0 + w * 16;                    // wave's q-row base

    __shared__ __align__(16) unsigned short Kb[KVB][136];   // 17.4 KB
    __shared__ __align__(16) unsigned short Vt[128][72];    // 18.4 KB
    __shared__ __align__(16) unsigned short Pl[8][16][72];  // 18.4 KB

    bf16x8 qf[4];
    {
        const unsigned short* qrow = qb_ + ((size_t)h * n + myrow0 + i) * HD;
#pragma unroll
        for (int kk = 0; kk < 4; ++kk)
            qf[kk] = as_frag(*(const uint4*)&qrow[kk * 32 + 8 * g]);
    }

    f32x4 o_acc[8] = {};
    float m_r[4], l_r[4];
#pragma unroll
    for (int r = 0; r < 4; ++r) { m_r[r] = 0.f; l_r[r] = 0.f; }

    for (int kt = t0; kt < t1; ++kt) {
        int k0 = kt * KVB;
        // stage K tile: 64x128 = 1024 16B chunks (2 iters x 512 thr)
#pragma unroll
        for (int u = 0; u < 2; ++u) {
            int c = tid + u * 512;
            int row = c >> 4, col = (c & 15) * 8;
            *(uint4*)&Kb[row][col] =
                *(const uint4*)&kb[((size_t)h * n + k0 + row) * HD + col];
        }
        // stage V^T tile: 128x64 = 1024 16B chunks
#pragma unroll
        for (int u = 0; u < 2; ++u) {
            int c = tid + u * 512;
            int row = c >> 3, col = (c & 7) * 8;
            *(uint4*)&Vt[row][col] =
                *(const uint4*)&vt[((size_t)h * HD + row) * n + k0 + col];
        }
        __syncthreads();

        // QK^T
        f32x4 s_acc[4] = {};
#pragma unroll
        for (int nb = 0; nb < 4; ++nb)
#pragma unroll
            for (int kk = 0; kk < 4; ++kk) {
                bf16x8 kf = as_frag(*(const uint4*)&Kb[nb * 16 + i][kk * 32 + 8 * g]);
                s_acc[nb] = __builtin_amdgcn_mfma_f32_16x16x32_bf16(
                    qf[kk], kf, s_acc[nb], 0, 0, 0);
            }

        // causal mask: only the last two tiles of the q-block touch the diagonal
        bool diagzone = (kt >= ntiles - 2);
        float mx[4];
#pragma unroll
        for (int r = 0; r < 4; ++r) mx[r] = NEGBIG;
#pragma unroll
        for (int nb = 0; nb < 4; ++nb)
#pragma unroll
            for (int r = 0; r < 4; ++r) {
                float sv = s_acc[nb][r];
                if (diagzone && (k0 + nb * 16 + i > myrow0 + 4 * g + r)) sv = NEGBIG;
                s_acc[nb][r] = sv;
                mx[r] = fmaxf(mx[r], sv);
            }
#pragma unroll
        for (int off = 1; off < 16; off <<= 1)
#pragma unroll
            for (int r = 0; r < 4; ++r)
                mx[r] = fmaxf(mx[r], __shfl_xor(mx[r], off));

        float alpha[4], sum[4];
#pragma unroll
        for (int r = 0; r < 4; ++r) {
            float mnew = fmaxf(m_r[r], mx[r]);
            alpha[r] = __expf(m_r[r] - mnew);
            m_r[r] = mnew;
            sum[r] = 0.f;
        }
#pragma unroll
        for (int nb = 0; nb < 4; ++nb)
#pragma unroll
            for (int r = 0; r < 4; ++r) {
                float p = __expf(s_acc[nb][r] - m_r[r]);
                s_acc[nb][r] = p;
                sum[r] += p;
            }
#pragma unroll
        for (int off = 1; off < 16; off <<= 1)
#pragma unroll
            for (int r = 0; r < 4; ++r)
                sum[r] += __shfl_xor(sum[r], off);
#pragma unroll
        for (int r = 0; r < 4; ++r) l_r[r] = l_r[r] * alpha[r] + sum[r];

#pragma unroll
        for (int d0 = 0; d0 < 8; ++d0)
#pragma unroll
            for (int r = 0; r < 4; ++r)
                o_acc[d0][r] *= alpha[r];

#pragma unroll
        for (int nb = 0; nb < 4; ++nb)
#pragma unroll
            for (int r = 0; r < 4; ++r)
                Pl[w][4 * g + r][nb * 16 + i] = f2bf(s_acc[nb][r]);
        __builtin_amdgcn_sched_barrier(0);

        // PV from LDS
#pragma unroll
        for (int kk = 0; kk < 2; ++kk) {
            bf16x8 pf = as_frag(*(const uint4*)&Pl[w][i][kk * 32 + 8 * g]);
#pragma unroll
            for (int d0 = 0; d0 < 8; ++d0) {
                bf16x8 vf = as_frag(*(const uint4*)&Vt[d0 * 16 + i][kk * 32 + 8 * g]);
                o_acc[d0] = __builtin_amdgcn_mfma_f32_16x16x32_bf16(
                    pf, vf, o_acc[d0], 0, 0, 0);
            }
        }
        __syncthreads();
    }

    // epilogue: write unnormalized partials
#pragma unroll
    for (int r = 0; r < 4; ++r) {
        int q = myrow0 + 4 * g + r;
        size_t idx = ((size_t)s * NHEADS + h) * n + q;
#pragma unroll
        for (int d0 = 0; d0 < 8; ++d0)
            o_part[idx * HD + d0 * 16 + i] = f2bf(o_acc[d0][r]);
        if (i == 0) { m_part[idx] = m_r[r]; l_part[idx] = l_r[r]; }
    }
}

// ---------------- combine NSPLIT partials ----------------
__global__ __launch_bounds__(256) void attn_combine_kernel(
        const unsigned short* __restrict__ o_part,
        const float* __restrict__ m_part, const float* __restrict__ l_part,
        unsigned short* __restrict__ ob, int n) {
    int q = blockIdx.x;
    int t = threadIdx.x;
    int h = t >> 4;
    int d = (t & 15) * 8;

    float m[NSPLIT], mstar = NEGBIG;
#pragma unroll
    for (int s = 0; s < NSPLIT; ++s) {
        m[s] = m_part[((size_t)s * NHEADS + h) * n + q];
        mstar = fmaxf(mstar, m[s]);
    }
    float l = 0.f, o[8] = {};
#pragma unroll
    for (int s = 0; s < NSPLIT; ++s) {
        if (m[s] < -1e4f) continue;          // empty split: contributes nothing
        float ws = __expf(m[s] - mstar);
        l += ws * l_part[((size_t)s * NHEADS + h) * n + q];
        U16x8 ov;
        ov.v = *(const uint4*)&o_part[(((size_t)s * NHEADS + h) * n + q) * HD + d];
#pragma unroll
        for (int e = 0; e < 8; ++e) o[e] += ws * bf2f(ov.h[e]);
    }
    float inv = 1.f / l;
    U16x8 w8;
#pragma unroll
    for (int e = 0; e < 8; ++e) w8.h[e] = f2bf(o[e] * inv);
    *(uint4*)&ob[(size_t)q * HIDDEN + h * HD + d] = w8.v;
}

extern "C" void kernel_launch(void* const* d_in, const int* in_sizes, int n_in,
                              void* d_out, int out_size, void* d_ws, size_t ws_size,
                              hipStream_t stream) {
    const float* x     = (const float*)d_in[0];
    const float* nsc   = (const float*)d_in[1];
    const float* qkv_w = (const float*)d_in[2];
    const float* qkv_b = (const float*)d_in[3];
    const float* out_w = (const float*)d_in[4];
    const float* out_b = (const float*)d_in[5];
    float* out = (float*)d_out;
    int n = in_sizes[0] / HIDDEN;     // 2048

    // Workspace (~77 MB). Lifetimes:
    //   wq, tb, cost, sint dead after fused QKV GEMM ->
    //   o_part aliases wq+tb (exactly 32 MiB), m/l_part alias cost/sint.
    char* w = (char*)d_ws;
    unsigned short* wq = (unsigned short*)w;  w += (size_t)QKV3 * HIDDEN * 2;   // 25.2MB
    unsigned short* tb = (unsigned short*)w;  w += (size_t)2048 * HIDDEN * 2;   // 8.4MB (n=2048)
    unsigned short* wo = (unsigned short*)w;  w += (size_t)HIDDEN * HIDDEN * 2; // 8.4MB
    unsigned short* qb = (unsigned short*)w;  w += (size_t)n * HIDDEN * 2;
    unsigned short* kb = (unsigned short*)w;  w += (size_t)n * HIDDEN * 2;
    unsigned short* vt = (unsigned short*)w;  w += (size_t)n * HIDDEN * 2;
    float* cost = (float*)w;                  w += (size_t)n * 64 * 4;
    float* sint = (float*)w;                  w += (size_t)n * 64 * 4;
    unsigned short* ob = (unsigned short*)w;  w += (size_t)n * HIDDEN * 2;

    unsigned short* o_part = wq;                         // 4*16*n*128*2 = 32MiB = wq+tb
    float* m_part = cost;                                // 4*16*n*4 = 512KB = cost
    float* l_part = sint;                                // = sint

    f32_to_bf16_kernel<<<(QKV3 * HIDDEN) / 1024, 256, 0, stream>>>(qkv_w, wq, QKV3 * HIDDEN);
    f32_to_bf16_kernel<<<(HIDDEN * HIDDEN) / 1024, 256, 0, stream>>>(out_w, wo, HIDDEN * HIDDEN);
    rope_table_kernel<<<n, 64, 0, stream>>>(cost, sint);
    rmsnorm_kernel<<<n, 256, 0, stream>>>(x, nsc, tb);
    gemm_qkv_fused_kernel<<<dim3(QKV3 / 128, n / 128), 256, 0, stream>>>(
        tb, wq, qkv_b, cost, sint, qb, kb, vt, n);
    attn_part_kernel<<<dim3((n / QB) * NHEADS * NSPLIT), 512, 0, stream>>>(
        qb, kb, vt, o_part, m_part, l_part, n);
    attn_combine_kernel<<<n, 256, 0, stream>>>(o_part, m_part, l_part, ob, n);
    gemm_bf16_kernel<<<dim3(HIDDEN / 128, n / 128), 256, 0, stream>>>(
        ob, wo, out_b, x, out, n, HIDDEN, HIDDEN);
}

// Round 21
// 225.808 us; speedup vs baseline: 1.1095x; 1.1095x over previous
//
#include <hip/hip_runtime.h>
#include <math.h>

#define HIDDEN 2048
#define NHEADS 16
#define HD     128
#define QKV3   6144
#define EPSV   1e-5f
#define NEGBIG -30000.0f

typedef short bf16x8 __attribute__((ext_vector_type(8)));
typedef float f32x4  __attribute__((ext_vector_type(4)));

__device__ inline unsigned short f2bf(float f) {
    unsigned u = __float_as_uint(f);
    u += 0x7fff + ((u >> 16) & 1);          // round-to-nearest-even
    return (unsigned short)(u >> 16);
}
__device__ inline float bf2f(unsigned short h) {
    return __uint_as_float(((unsigned)h) << 16);
}

union FragCast { uint4 u; bf16x8 v; };
__device__ inline bf16x8 as_frag(uint4 x) { FragCast c; c.u = x; return c.v; }
union U16x8 { unsigned short h[8]; uint4 v; };

// async global->LDS, 16B per lane (wave-uniform LDS base, HW linear scatter)
__device__ __forceinline__ void gload16(const void* gsrc, void* ldst) {
    typedef __attribute__((address_space(1))) const char GC;
    typedef __attribute__((address_space(3))) char LC;
    __builtin_amdgcn_global_load_lds((GC*)(unsigned long long)gsrc,
                                     (LC*)(unsigned long long)ldst, 16, 0, 0);
}

// ---------------- fp32 -> bf16 conversion (both weights, one launch) --------
__global__ __launch_bounds__(256) void f32_to_bf16_dual_kernel(
        const float* __restrict__ in1, unsigned short* __restrict__ out1, int c1,
        const float* __restrict__ in2, unsigned short* __restrict__ out2, int c2) {
    int i = (blockIdx.x * 256 + threadIdx.x) * 4;
    if (i < c1) {
        float4 v = *(const float4*)&in1[i];
        ushort4 o = {f2bf(v.x), f2bf(v.y), f2bf(v.z), f2bf(v.w)};
        *(ushort4*)&out1[i] = o;
    } else if (i - c1 < c2) {
        int j = i - c1;                      // c1 % 4 == 0 -> segment aligned
        float4 v = *(const float4*)&in2[j];
        ushort4 o = {f2bf(v.x), f2bf(v.y), f2bf(v.z), f2bf(v.w)};
        *(ushort4*)&out2[j] = o;
    }
}

// ---------------- RoPE cos/sin table ----------------
__global__ void rope_table_kernel(float* __restrict__ cost, float* __restrict__ sint) {
    int pos = blockIdx.x;
    int i   = threadIdx.x;              // 0..63
    float inv = exp2f((float)i * (-17.1946030f / 64.0f));   // 150000^(-i/64)
    float f   = (float)pos * inv;
    cost[pos * 64 + i] = cosf(f);
    sint[pos * 64 + i] = sinf(f);
}

// ---------------- RMSNorm (fp32 in, bf16 out) ----------------
__global__ __launch_bounds__(256) void rmsnorm_kernel(
        const float* __restrict__ x, const float* __restrict__ scale,
        unsigned short* __restrict__ t) {
    int row = blockIdx.x;
    int tid = threadIdx.x;
    const float* xr = x + (size_t)row * HIDDEN;
    unsigned short* tr = t + (size_t)row * HIDDEN;

    float4 v[2];
    float ss = 0.f;
#pragma unroll
    for (int u = 0; u < 2; ++u) {
        v[u] = ((const float4*)xr)[tid + u * 256];
        ss += v[u].x * v[u].x + v[u].y * v[u].y + v[u].z * v[u].z + v[u].w * v[u].w;
    }
#pragma unroll
    for (int off = 32; off; off >>= 1) ss += __shfl_xor(ss, off);
    __shared__ float wsum[4];
    if ((tid & 63) == 0) wsum[tid >> 6] = ss;
    __syncthreads();
    float tot = wsum[0] + wsum[1] + wsum[2] + wsum[3];
    float r = rsqrtf(tot / (float)HIDDEN + EPSV);
#pragma unroll
    for (int u = 0; u < 2; ++u) {
        int idx = tid + u * 256;
        float4 sc = ((const float4*)scale)[idx];
        ushort4 o = {f2bf(v[u].x * r * sc.x), f2bf(v[u].y * r * sc.y),
                     f2bf(v[u].z * r * sc.z), f2bf(v[u].w * r * sc.w)};
        ((ushort4*)tr)[idx] = o;
    }
}

// ---------------- generic bf16 MFMA NT GEMM (BK=32, r17-verified) ----------
__global__ __launch_bounds__(256) void gemm_bf16_kernel(
        const unsigned short* __restrict__ A, const unsigned short* __restrict__ B,
        const float* __restrict__ bias, const float* __restrict__ resid,
        float* __restrict__ C, int M, int N, int K) {
    __shared__ __align__(16) unsigned short As[128][32];
    __shared__ __align__(16) unsigned short Bs[128][32];

    int tid  = threadIdx.x;
    int bn   = blockIdx.x * 128;
    int bm   = blockIdx.y * 128;
    int lane = tid & 63;
    int wid  = tid >> 6;
    int wr   = wid >> 1;
    int wc   = wid & 1;
    int fr   = lane & 15;
    int fq   = lane >> 4;

    f32x4 acc[4][4] = {};

    const int nk = K >> 5;
    for (int kt = 0; kt < nk; ++kt) {
        int k0 = kt << 5;
#pragma unroll
        for (int u = 0; u < 2; ++u) {
            int c   = tid + u * 256;
            int row = c >> 2;
            int kk  = (c & 3) * 8;
            gload16(&A[(size_t)(bm + row) * K + k0 + kk], &As[(wid << 4) + (u << 6)][0]);
            gload16(&B[(size_t)(bn + row) * K + k0 + kk], &Bs[(wid << 4) + (u << 6)][0]);
        }
        __syncthreads();

        bf16x8 af[4], bfr[4];
#pragma unroll
        for (int i = 0; i < 4; ++i) {
            af[i]  = as_frag(*(const uint4*)&As[wr * 64 + i * 16 + fr][fq * 8]);
            bfr[i] = as_frag(*(const uint4*)&Bs[wc * 64 + i * 16 + fr][fq * 8]);
        }
#pragma unroll
        for (int mi = 0; mi < 4; ++mi)
#pragma unroll
            for (int ni = 0; ni < 4; ++ni)
                acc[mi][ni] = __builtin_amdgcn_mfma_f32_16x16x32_bf16(
                    af[mi], bfr[ni], acc[mi][ni], 0, 0, 0);
        __syncthreads();
    }

#pragma unroll
    for (int ni = 0; ni < 4; ++ni) {
        int col = bn + wc * 64 + ni * 16 + fr;
        float bb = bias[col];
#pragma unroll
        for (int mi = 0; mi < 4; ++mi) {
#pragma unroll
            for (int r = 0; r < 4; ++r) {
                int row = bm + wr * 64 + mi * 16 + fq * 4 + r;
                float v = acc[mi][ni][r] + bb;
                if (resid) v += resid[(size_t)row * N + col];
                C[(size_t)row * N + col] = v;
            }
        }
    }
}

// ---------------- fused QKV GEMM (BK=32, r17-verified): RoPE+repack+V-T ----
__global__ __launch_bounds__(256) void gemm_qkv_fused_kernel(
        const unsigned short* __restrict__ A,    // tb [n][2048] bf16
        const unsigned short* __restrict__ B,    // wq [6144][2048] bf16
        const float* __restrict__ bias,          // qkv_b [6144]
        const float* __restrict__ cost, const float* __restrict__ sint,
        unsigned short* __restrict__ qb, unsigned short* __restrict__ kb,
        unsigned short* __restrict__ vt, int n) {
    const int K = HIDDEN;
    __shared__ __align__(16) char smem[33792];   // max(As+Bs 16KB, Ct 33792B)
    auto As = (unsigned short(*)[32])smem;
    auto Bs = (unsigned short(*)[32])(smem + 8192);
    auto Ct = (unsigned short(*)[132])smem;      // [128][132] bf16, +4 pad

    int tid  = threadIdx.x;
    int bn   = blockIdx.x * 128;
    int bm   = blockIdx.y * 128;
    int lane = tid & 63;
    int wid  = tid >> 6;
    int wr   = wid >> 1;
    int wc   = wid & 1;
    int fr   = lane & 15;
    int fq   = lane >> 4;

    f32x4 acc[4][4] = {};

    const int nk = K >> 5;
    for (int kt = 0; kt < nk; ++kt) {
        int k0 = kt << 5;
#pragma unroll
        for (int u = 0; u < 2; ++u) {
            int c   = tid + u * 256;
            int row = c >> 2;
            int kk  = (c & 3) * 8;
            gload16(&A[(size_t)(bm + row) * K + k0 + kk], &As[(wid << 4) + (u << 6)][0]);
            gload16(&B[(size_t)(bn + row) * K + k0 + kk], &Bs[(wid << 4) + (u << 6)][0]);
        }
        __syncthreads();

        bf16x8 af[4], bfr[4];
#pragma unroll
        for (int i = 0; i < 4; ++i) {
            af[i]  = as_frag(*(const uint4*)&As[wr * 64 + i * 16 + fr][fq * 8]);
            bfr[i] = as_frag(*(const uint4*)&Bs[wc * 64 + i * 16 + fr][fq * 8]);
        }
#pragma unroll
        for (int mi = 0; mi < 4; ++mi)
#pragma unroll
            for (int ni = 0; ni < 4; ++ni)
                acc[mi][ni] = __builtin_amdgcn_mfma_f32_16x16x32_bf16(
                    af[mi], bfr[ni], acc[mi][ni], 0, 0, 0);
        __syncthreads();                          // also frees As/Bs for Ct
    }

    // phase 1: acc (+bias) -> Ct bf16
#pragma unroll
    for (int ni = 0; ni < 4; ++ni) {
        int lc = wc * 64 + ni * 16 + fr;
        float bb = bias[bn + lc];
#pragma unroll
        for (int mi = 0; mi < 4; ++mi)
#pragma unroll
            for (int r = 0; r < 4; ++r)
                Ct[wr * 64 + mi * 16 + fq * 4 + r][lc] = f2bf(acc[mi][ni][r] + bb);
    }
    __syncthreads();

    // phase 2: region store
    int region = bn >> 11;            // 0=q, 1=k, 2=v
    int h      = (bn & 2047) >> 7;    // head
    if (region == 2) {
        // v: vt[(h*128 + d)*n + pos], transpose from Ct[pos_local][d]
#pragma unroll
        for (int u = 0; u < 8; ++u) {
            int c2 = tid + u * 256;               // 0..2047
            int d  = c2 >> 4;                     // 0..127
            int r0 = (c2 & 15) * 8;               // 0..120
            U16x8 o;
#pragma unroll
            for (int e = 0; e < 8; ++e) o.h[e] = Ct[r0 + e][d];
            *(uint4*)&vt[((size_t)h * HD + d) * n + bm + r0] = o.v;
        }
    } else {
        unsigned short* dst = region ? kb : qb;
        float scq = region ? 1.0f : 0.088388347648318447f;   // q: 1/sqrt(128)
#pragma unroll
        for (int u = 0; u < 4; ++u) {
            int t2 = tid + u * 256;               // 0..1023
            int rr = t2 >> 3;                     // 0..127
            int d0 = (t2 & 7) * 8;                // 0..56
            int pos = bm + rr;
            float4 c0 = *(const float4*)&cost[pos * 64 + d0];
            float4 c1 = *(const float4*)&cost[pos * 64 + d0 + 4];
            float4 s0 = *(const float4*)&sint[pos * 64 + d0];
            float4 s1 = *(const float4*)&sint[pos * 64 + d0 + 4];
            float cv[8] = {c0.x, c0.y, c0.z, c0.w, c1.x, c1.y, c1.z, c1.w};
            float sv[8] = {s0.x, s0.y, s0.z, s0.w, s1.x, s1.y, s1.z, s1.w};
            U16x8 lo, hi;
#pragma unroll
            for (int e = 0; e < 8; ++e) {
                float x1 = bf2f(Ct[rr][d0 + e]);
                float x2 = bf2f(Ct[rr][d0 + 64 + e]);
                lo.h[e] = f2bf((x1 * cv[e] - x2 * sv[e]) * scq);
                hi.h[e] = f2bf((x2 * cv[e] + x1 * sv[e]) * scq);
            }
            unsigned short* drow = dst + ((size_t)h * n + pos) * HD;
            *(uint4*)&drow[d0]      = lo.v;
            *(uint4*)&drow[d0 + 64] = hi.v;
        }
    }
}

// ---------------- split-KV MFMA flash attention (partials) ----------------
// 1-D grid (n/128 * NHEADS * NSPLIT), block 512 = 8 waves x 16 q-rows.
// Head->XCD pinning: fid = h + 16*rest => fid%8 == h%8 (2 heads per XCD L2).
#define QB  128
#define KVB 64
#define NSPLIT 4
__global__ __launch_bounds__(512) void attn_part_kernel(
        const unsigned short* __restrict__ qb_,  // [H][n][128] (pre-scaled)
        const unsigned short* __restrict__ kb,   // [H][n][128]
        const unsigned short* __restrict__ vt,   // [H][128][n]
        unsigned short* __restrict__ o_part,     // [S][H][n][128] bf16
        float* __restrict__ m_part,              // [S][H][n]
        float* __restrict__ l_part, int n) {
    int nqb  = n / QB;                           // 16
    int fid  = blockIdx.x;
    int h    = fid & 15;                         // NHEADS-1
    int rest = fid >> 4;                         // 0 .. nqb*NSPLIT-1
    int qbi  = (nqb - 1) - (rest % nqb);         // long q-blocks first
    int s    = rest / nqb;
    int q0   = qbi * QB;
    int ntiles = (q0 + QB) / KVB;                // 2*(qbi+1)
    int chunk  = (ntiles + NSPLIT - 1) >> 2;
    int t0 = s * chunk;
    int t1 = t0 + chunk; if (t1 > ntiles) t1 = ntiles;
    int tid = threadIdx.x;

    if (t0 >= ntiles) {                          // empty split: weight-0 partial
        if (tid < QB) {
            size_t idx = ((size_t)s * NHEADS + h) * n + q0 + tid;
            m_part[idx] = NEGBIG;
            l_part[idx] = 0.f;
            for (int e = 0; e < HD / 8; ++e) {
                U16x8 z; z.v = make_uint4(0, 0, 0, 0);
                *(uint4*)&o_part[idx * HD + e * 8] = z.v;
            }
        }
        return;
    }

    int lane = tid & 63, w = tid >> 6;           // w = 0..7
    int g = lane >> 4, i = lane & 15;
    int myrow0 = q0 + w * 16;                    // wave's q-row base

    __shared__ __align__(16) unsigned short Kb[KVB][136];   // 17.4 KB
    __shared__ __align__(16) unsigned short Vt[128][72];    // 18.4 KB
    __shared__ __align__(16) unsigned short Pl[8][16][72];  // 18.4 KB

    bf16x8 qf[4];
    {
        const unsigned short* qrow = qb_ + ((size_t)h * n + myrow0 + i) * HD;
#pragma unroll
        for (int kk = 0; kk < 4; ++kk)
            qf[kk] = as_frag(*(const uint4*)&qrow[kk * 32 + 8 * g]);
    }

    f32x4 o_acc[8] = {};
    float m_r[4], l_r[4];
#pragma unroll
    for (int r = 0; r < 4; ++r) { m_r[r] = 0.f; l_r[r] = 0.f; }

    for (int kt = t0; kt < t1; ++kt) {
        int k0 = kt * KVB;
        // stage K tile: 64x128 = 1024 16B chunks (2 iters x 512 thr)
#pragma unroll
        for (int u = 0; u < 2; ++u) {
            int c = tid + u * 512;
            int row = c >> 4, col = (c & 15) * 8;
            *(uint4*)&Kb[row][col] =
                *(const uint4*)&kb[((size_t)h * n + k0 + row) * HD + col];
        }
        // stage V^T tile: 128x64 = 1024 16B chunks
#pragma unroll
        for (int u = 0; u < 2; ++u) {
            int c = tid + u * 512;
            int row = c >> 3, col = (c & 7) * 8;
            *(uint4*)&Vt[row][col] =
                *(const uint4*)&vt[((size_t)h * HD + row) * n + k0 + col];
        }
        __syncthreads();

        // QK^T
        f32x4 s_acc[4] = {};
#pragma unroll
        for (int nb = 0; nb < 4; ++nb)
#pragma unroll
            for (int kk = 0; kk < 4; ++kk) {
                bf16x8 kf = as_frag(*(const uint4*)&Kb[nb * 16 + i][kk * 32 + 8 * g]);
                s_acc[nb] = __builtin_amdgcn_mfma_f32_16x16x32_bf16(
                    qf[kk], kf, s_acc[nb], 0, 0, 0);
            }

        // causal mask: only the last two tiles of the q-block touch the diagonal
        bool diagzone = (kt >= ntiles - 2);
        float mx[4];
#pragma unroll
        for (int r = 0; r < 4; ++r) mx[r] = NEGBIG;
#pragma unroll
        for (int nb = 0; nb < 4; ++nb)
#pragma unroll
            for (int r = 0; r < 4; ++r) {
                float sv = s_acc[nb][r];
                if (diagzone && (k0 + nb * 16 + i > myrow0 + 4 * g + r)) sv = NEGBIG;
                s_acc[nb][r] = sv;
                mx[r] = fmaxf(mx[r], sv);
            }
#pragma unroll
        for (int off = 1; off < 16; off <<= 1)
#pragma unroll
            for (int r = 0; r < 4; ++r)
                mx[r] = fmaxf(mx[r], __shfl_xor(mx[r], off));

        float alpha[4], sum[4];
#pragma unroll
        for (int r = 0; r < 4; ++r) {
            float mnew = fmaxf(m_r[r], mx[r]);
            alpha[r] = __expf(m_r[r] - mnew);
            m_r[r] = mnew;
            sum[r] = 0.f;
        }
#pragma unroll
        for (int nb = 0; nb < 4; ++nb)
#pragma unroll
            for (int r = 0; r < 4; ++r) {
                float p = __expf(s_acc[nb][r] - m_r[r]);
                s_acc[nb][r] = p;
                sum[r] += p;
            }
#pragma unroll
        for (int off = 1; off < 16; off <<= 1)
#pragma unroll
            for (int r = 0; r < 4; ++r)
                sum[r] += __shfl_xor(sum[r], off);
#pragma unroll
        for (int r = 0; r < 4; ++r) l_r[r] = l_r[r] * alpha[r] + sum[r];

#pragma unroll
        for (int d0 = 0; d0 < 8; ++d0)
#pragma unroll
            for (int r = 0; r < 4; ++r)
                o_acc[d0][r] *= alpha[r];

#pragma unroll
        for (int nb = 0; nb < 4; ++nb)
#pragma unroll
            for (int r = 0; r < 4; ++r)
                Pl[w][4 * g + r][nb * 16 + i] = f2bf(s_acc[nb][r]);
        __builtin_amdgcn_sched_barrier(0);

        // PV from LDS
#pragma unroll
        for (int kk = 0; kk < 2; ++kk) {
            bf16x8 pf = as_frag(*(const uint4*)&Pl[w][i][kk * 32 + 8 * g]);
#pragma unroll
            for (int d0 = 0; d0 < 8; ++d0) {
                bf16x8 vf = as_frag(*(const uint4*)&Vt[d0 * 16 + i][kk * 32 + 8 * g]);
                o_acc[d0] = __builtin_amdgcn_mfma_f32_16x16x32_bf16(
                    pf, vf, o_acc[d0], 0, 0, 0);
            }
        }
        __syncthreads();
    }

    // epilogue: write unnormalized partials
#pragma unroll
    for (int r = 0; r < 4; ++r) {
        int q = myrow0 + 4 * g + r;
        size_t idx = ((size_t)s * NHEADS + h) * n + q;
#pragma unroll
        for (int d0 = 0; d0 < 8; ++d0)
            o_part[idx * HD + d0 * 16 + i] = f2bf(o_acc[d0][r]);
        if (i == 0) { m_part[idx] = m_r[r]; l_part[idx] = l_r[r]; }
    }
}

// ---------------- combine NSPLIT partials ----------------
__global__ __launch_bounds__(256) void attn_combine_kernel(
        const unsigned short* __restrict__ o_part,
        const float* __restrict__ m_part, const float* __restrict__ l_part,
        unsigned short* __restrict__ ob, int n) {
    int q = blockIdx.x;
    int t = threadIdx.x;
    int h = t >> 4;
    int d = (t & 15) * 8;

    float m[NSPLIT], mstar = NEGBIG;
#pragma unroll
    for (int s = 0; s < NSPLIT; ++s) {
        m[s] = m_part[((size_t)s * NHEADS + h) * n + q];
        mstar = fmaxf(mstar, m[s]);
    }
    float l = 0.f, o[8] = {};
#pragma unroll
    for (int s = 0; s < NSPLIT; ++s) {
        if (m[s] < -1e4f) continue;          // empty split: contributes nothing
        float ws = __expf(m[s] - mstar);
        l += ws * l_part[((size_t)s * NHEADS + h) * n + q];
        U16x8 ov;
        ov.v = *(const uint4*)&o_part[(((size_t)s * NHEADS + h) * n + q) * HD + d];
#pragma unroll
        for (int e = 0; e < 8; ++e) o[e] += ws * bf2f(ov.h[e]);
    }
    float inv = 1.f / l;
    U16x8 w8;
#pragma unroll
    for (int e = 0; e < 8; ++e) w8.h[e] = f2bf(o[e] * inv);
    *(uint4*)&ob[(size_t)q * HIDDEN + h * HD + d] = w8.v;
}

extern "C" void kernel_launch(void* const* d_in, const int* in_sizes, int n_in,
                              void* d_out, int out_size, void* d_ws, size_t ws_size,
                              hipStream_t stream) {
    const float* x     = (const float*)d_in[0];
    const float* nsc   = (const float*)d_in[1];
    const float* qkv_w = (const float*)d_in[2];
    const float* qkv_b = (const float*)d_in[3];
    const float* out_w = (const float*)d_in[4];
    const float* out_b = (const float*)d_in[5];
    float* out = (float*)d_out;
    int n = in_sizes[0] / HIDDEN;     // 2048

    // Workspace (~77 MB). Lifetimes:
    //   wq, tb, cost, sint dead after fused QKV GEMM ->
    //   o_part aliases wq+tb (exactly 32 MiB), m/l_part alias cost/sint.
    char* w = (char*)d_ws;
    unsigned short* wq = (unsigned short*)w;  w += (size_t)QKV3 * HIDDEN * 2;   // 25.2MB
    unsigned short* tb = (unsigned short*)w;  w += (size_t)2048 * HIDDEN * 2;   // 8.4MB (n=2048)
    unsigned short* wo = (unsigned short*)w;  w += (size_t)HIDDEN * HIDDEN * 2; // 8.4MB
    unsigned short* qb = (unsigned short*)w;  w += (size_t)n * HIDDEN * 2;
    unsigned short* kb = (unsigned short*)w;  w += (size_t)n * HIDDEN * 2;
    unsigned short* vt = (unsigned short*)w;  w += (size_t)n * HIDDEN * 2;
    float* cost = (float*)w;                  w += (size_t)n * 64 * 4;
    float* sint = (float*)w;                  w += (size_t)n * 64 * 4;
    unsigned short* ob = (unsigned short*)w;  w += (size_t)n * HIDDEN * 2;

    unsigned short* o_part = wq;                         // 4*16*n*128*2 = 32MiB = wq+tb
    float* m_part = cost;                                // 4*16*n*4 = 512KB = cost
    float* l_part = sint;                                // = sint

    int c1 = QKV3 * HIDDEN, c2 = HIDDEN * HIDDEN;
    f32_to_bf16_dual_kernel<<<(c1 + c2) / 1024, 256, 0, stream>>>(
        qkv_w, wq, c1, out_w, wo, c2);
    rope_table_kernel<<<n, 64, 0, stream>>>(cost, sint);
    rmsnorm_kernel<<<n, 256, 0, stream>>>(x, nsc, tb);
    gemm_qkv_fused_kernel<<<dim3(QKV3 / 128, n / 128), 256, 0, stream>>>(
        tb, wq, qkv_b, cost, sint, qb, kb, vt, n);
    attn_part_kernel<<<dim3((n / QB) * NHEADS * NSPLIT), 512, 0, stream>>>(
        qb, kb, vt, o_part, m_part, l_part, n);
    attn_combine_kernel<<<n, 256, 0, stream>>>(o_part, m_part, l_part, ob, n);
    gemm_bf16_kernel<<<dim3(HIDDEN / 128, n / 128), 256, 0, stream>>>(
        ob, wo, out_b, x, out, n, HIDDEN, HIDDEN);
}

// Round 22
// 222.100 us; speedup vs baseline: 1.1280x; 1.0167x over previous
//
#include <hip/hip_runtime.h>
#include <math.h>

#define HIDDEN 2048
#define NHEADS 16
#define HD     128
#define QKV3   6144
#define EPSV   1e-5f
#define NEGBIG -30000.0f

typedef short bf16x8 __attribute__((ext_vector_type(8)));
typedef float f32x4  __attribute__((ext_vector_type(4)));

__device__ inline unsigned short f2bf(float f) {
    unsigned u = __float_as_uint(f);
    u += 0x7fff + ((u >> 16) & 1);          // round-to-nearest-even
    return (unsigned short)(u >> 16);
}
__device__ inline float bf2f(unsigned short h) {
    return __uint_as_float(((unsigned)h) << 16);
}

union FragCast { uint4 u; bf16x8 v; };
__device__ inline bf16x8 as_frag(uint4 x) { FragCast c; c.u = x; return c.v; }
union U16x8 { unsigned short h[8]; uint4 v; };

// async global->LDS, 16B per lane (wave-uniform LDS base, HW linear scatter)
__device__ __forceinline__ void gload16(const void* gsrc, void* ldst) {
    typedef __attribute__((address_space(1))) const char GC;
    typedef __attribute__((address_space(3))) char LC;
    __builtin_amdgcn_global_load_lds((GC*)(unsigned long long)gsrc,
                                     (LC*)(unsigned long long)ldst, 16, 0, 0);
}

// ---------------- fused prologue: weight converts + RoPE table + RMSNorm ----
// Independent jobs dispatched by block range in ONE launch (saves 2 launch
// gaps; table/rmsnorm ride in the convert's shadow).
__global__ __launch_bounds__(256) void prologue_kernel(
        const float* __restrict__ qkv_w, unsigned short* __restrict__ wq, int c1,
        const float* __restrict__ out_w, unsigned short* __restrict__ wo, int c2,
        float* __restrict__ cost, float* __restrict__ sint,
        const float* __restrict__ x, const float* __restrict__ scale,
        unsigned short* __restrict__ tb, int n) {
    int nconv = (c1 + c2) >> 10;            // 256 thr x 4 elems
    int ntab  = n >> 2;                     // 4 positions per block
    int b   = blockIdx.x;
    int tid = threadIdx.x;

    if (b < nconv) {                        // ---- weight fp32 -> bf16
        int i = (b * 256 + tid) * 4;
        if (i < c1) {
            float4 v = *(const float4*)&qkv_w[i];
            ushort4 o = {f2bf(v.x), f2bf(v.y), f2bf(v.z), f2bf(v.w)};
            *(ushort4*)&wq[i] = o;
        } else if (i - c1 < c2) {
            int j = i - c1;                 // c1 % 4 == 0 -> aligned
            float4 v = *(const float4*)&out_w[j];
            ushort4 o = {f2bf(v.x), f2bf(v.y), f2bf(v.z), f2bf(v.w)};
            *(ushort4*)&wo[j] = o;
        }
        return;
    }
    b -= nconv;
    if (b < ntab) {                         // ---- RoPE cos/sin table
        int pos = b * 4 + (tid >> 6);
        int i   = tid & 63;
        float inv = exp2f((float)i * (-17.1946030f / 64.0f));   // 150000^(-i/64)
        float f   = (float)pos * inv;
        cost[pos * 64 + i] = cosf(f);
        sint[pos * 64 + i] = sinf(f);
        return;
    }
    b -= ntab;                              // ---- RMSNorm row b
    {
        int row = b;
        const float* xr = x + (size_t)row * HIDDEN;
        unsigned short* tr = tb + (size_t)row * HIDDEN;

        float4 v[2];
        float ss = 0.f;
#pragma unroll
        for (int u = 0; u < 2; ++u) {
            v[u] = ((const float4*)xr)[tid + u * 256];
            ss += v[u].x * v[u].x + v[u].y * v[u].y + v[u].z * v[u].z + v[u].w * v[u].w;
        }
#pragma unroll
        for (int off = 32; off; off >>= 1) ss += __shfl_xor(ss, off);
        __shared__ float wsum[4];
        if ((tid & 63) == 0) wsum[tid >> 6] = ss;
        __syncthreads();
        float tot = wsum[0] + wsum[1] + wsum[2] + wsum[3];
        float r = rsqrtf(tot / (float)HIDDEN + EPSV);
#pragma unroll
        for (int u = 0; u < 2; ++u) {
            int idx = tid + u * 256;
            float4 sc = ((const float4*)scale)[idx];
            ushort4 o = {f2bf(v[u].x * r * sc.x), f2bf(v[u].y * r * sc.y),
                         f2bf(v[u].z * r * sc.z), f2bf(v[u].w * r * sc.w)};
            ((ushort4*)tr)[idx] = o;
        }
    }
}

// ---------------- generic bf16 MFMA NT GEMM (BK=32, r17-verified) ----------
__global__ __launch_bounds__(256) void gemm_bf16_kernel(
        const unsigned short* __restrict__ A, const unsigned short* __restrict__ B,
        const float* __restrict__ bias, const float* __restrict__ resid,
        float* __restrict__ C, int M, int N, int K) {
    __shared__ __align__(16) unsigned short As[128][32];
    __shared__ __align__(16) unsigned short Bs[128][32];

    int tid  = threadIdx.x;
    int bn   = blockIdx.x * 128;
    int bm   = blockIdx.y * 128;
    int lane = tid & 63;
    int wid  = tid >> 6;
    int wr   = wid >> 1;
    int wc   = wid & 1;
    int fr   = lane & 15;
    int fq   = lane >> 4;

    f32x4 acc[4][4] = {};

    const int nk = K >> 5;
    for (int kt = 0; kt < nk; ++kt) {
        int k0 = kt << 5;
#pragma unroll
        for (int u = 0; u < 2; ++u) {
            int c   = tid + u * 256;
            int row = c >> 2;
            int kk  = (c & 3) * 8;
            gload16(&A[(size_t)(bm + row) * K + k0 + kk], &As[(wid << 4) + (u << 6)][0]);
            gload16(&B[(size_t)(bn + row) * K + k0 + kk], &Bs[(wid << 4) + (u << 6)][0]);
        }
        __syncthreads();

        bf16x8 af[4], bfr[4];
#pragma unroll
        for (int i = 0; i < 4; ++i) {
            af[i]  = as_frag(*(const uint4*)&As[wr * 64 + i * 16 + fr][fq * 8]);
            bfr[i] = as_frag(*(const uint4*)&Bs[wc * 64 + i * 16 + fr][fq * 8]);
        }
#pragma unroll
        for (int mi = 0; mi < 4; ++mi)
#pragma unroll
            for (int ni = 0; ni < 4; ++ni)
                acc[mi][ni] = __builtin_amdgcn_mfma_f32_16x16x32_bf16(
                    af[mi], bfr[ni], acc[mi][ni], 0, 0, 0);
        __syncthreads();
    }

#pragma unroll
    for (int ni = 0; ni < 4; ++ni) {
        int col = bn + wc * 64 + ni * 16 + fr;
        float bb = bias[col];
#pragma unroll
        for (int mi = 0; mi < 4; ++mi) {
#pragma unroll
            for (int r = 0; r < 4; ++r) {
                int row = bm + wr * 64 + mi * 16 + fq * 4 + r;
                float v = acc[mi][ni][r] + bb;
                if (resid) v += resid[(size_t)row * N + col];
                C[(size_t)row * N + col] = v;
            }
        }
    }
}

// ---------------- fused QKV GEMM (BK=32, r17-verified): RoPE+repack+V-T ----
__global__ __launch_bounds__(256) void gemm_qkv_fused_kernel(
        const unsigned short* __restrict__ A,    // tb [n][2048] bf16
        const unsigned short* __restrict__ B,    // wq [6144][2048] bf16
        const float* __restrict__ bias,          // qkv_b [6144]
        const float* __restrict__ cost, const float* __restrict__ sint,
        unsigned short* __restrict__ qb, unsigned short* __restrict__ kb,
        unsigned short* __restrict__ vt, int n) {
    const int K = HIDDEN;
    __shared__ __align__(16) char smem[33792];   // max(As+Bs 16KB, Ct 33792B)
    auto As = (unsigned short(*)[32])smem;
    auto Bs = (unsigned short(*)[32])(smem + 8192);
    auto Ct = (unsigned short(*)[132])smem;      // [128][132] bf16, +4 pad

    int tid  = threadIdx.x;
    int bn   = blockIdx.x * 128;
    int bm   = blockIdx.y * 128;
    int lane = tid & 63;
    int wid  = tid >> 6;
    int wr   = wid >> 1;
    int wc   = wid & 1;
    int fr   = lane & 15;
    int fq   = lane >> 4;

    f32x4 acc[4][4] = {};

    const int nk = K >> 5;
    for (int kt = 0; kt < nk; ++kt) {
        int k0 = kt << 5;
#pragma unroll
        for (int u = 0; u < 2; ++u) {
            int c   = tid + u * 256;
            int row = c >> 2;
            int kk  = (c & 3) * 8;
            gload16(&A[(size_t)(bm + row) * K + k0 + kk], &As[(wid << 4) + (u << 6)][0]);
            gload16(&B[(size_t)(bn + row) * K + k0 + kk], &Bs[(wid << 4) + (u << 6)][0]);
        }
        __syncthreads();

        bf16x8 af[4], bfr[4];
#pragma unroll
        for (int i = 0; i < 4; ++i) {
            af[i]  = as_frag(*(const uint4*)&As[wr * 64 + i * 16 + fr][fq * 8]);
            bfr[i] = as_frag(*(const uint4*)&Bs[wc * 64 + i * 16 + fr][fq * 8]);
        }
#pragma unroll
        for (int mi = 0; mi < 4; ++mi)
#pragma unroll
            for (int ni = 0; ni < 4; ++ni)
                acc[mi][ni] = __builtin_amdgcn_mfma_f32_16x16x32_bf16(
                    af[mi], bfr[ni], acc[mi][ni], 0, 0, 0);
        __syncthreads();                          // also frees As/Bs for Ct
    }

    // phase 1: acc (+bias) -> Ct bf16
#pragma unroll
    for (int ni = 0; ni < 4; ++ni) {
        int lc = wc * 64 + ni * 16 + fr;
        float bb = bias[bn + lc];
#pragma unroll
        for (int mi = 0; mi < 4; ++mi)
#pragma unroll
            for (int r = 0; r < 4; ++r)
                Ct[wr * 64 + mi * 16 + fq * 4 + r][lc] = f2bf(acc[mi][ni][r] + bb);
    }
    __syncthreads();

    // phase 2: region store
    int region = bn >> 11;            // 0=q, 1=k, 2=v
    int h      = (bn & 2047) >> 7;    // head
    if (region == 2) {
        // v: vt[(h*128 + d)*n + pos], transpose from Ct[pos_local][d]
#pragma unroll
        for (int u = 0; u < 8; ++u) {
            int c2 = tid + u * 256;               // 0..2047
            int d  = c2 >> 4;                     // 0..127
            int r0 = (c2 & 15) * 8;               // 0..120
            U16x8 o;
#pragma unroll
            for (int e = 0; e < 8; ++e) o.h[e] = Ct[r0 + e][d];
            *(uint4*)&vt[((size_t)h * HD + d) * n + bm + r0] = o.v;
        }
    } else {
        unsigned short* dst = region ? kb : qb;
        float scq = region ? 1.0f : 0.088388347648318447f;   // q: 1/sqrt(128)
#pragma unroll
        for (int u = 0; u < 4; ++u) {
            int t2 = tid + u * 256;               // 0..1023
            int rr = t2 >> 3;                     // 0..127
            int d0 = (t2 & 7) * 8;                // 0..56
            int pos = bm + rr;
            float4 c0 = *(const float4*)&cost[pos * 64 + d0];
            float4 c1 = *(const float4*)&cost[pos * 64 + d0 + 4];
            float4 s0 = *(const float4*)&sint[pos * 64 + d0];
            float4 s1 = *(const float4*)&sint[pos * 64 + d0 + 4];
            float cv[8] = {c0.x, c0.y, c0.z, c0.w, c1.x, c1.y, c1.z, c1.w};
            float sv[8] = {s0.x, s0.y, s0.z, s0.w, s1.x, s1.y, s1.z, s1.w};
            U16x8 lo, hi;
#pragma unroll
            for (int e = 0; e < 8; ++e) {
                float x1 = bf2f(Ct[rr][d0 + e]);
                float x2 = bf2f(Ct[rr][d0 + 64 + e]);
                lo.h[e] = f2bf((x1 * cv[e] - x2 * sv[e]) * scq);
                hi.h[e] = f2bf((x2 * cv[e] + x1 * sv[e]) * scq);
            }
            unsigned short* drow = dst + ((size_t)h * n + pos) * HD;
            *(uint4*)&drow[d0]      = lo.v;
            *(uint4*)&drow[d0 + 64] = hi.v;
        }
    }
}

// ---------------- split-KV MFMA flash attention (partials) ----------------
// 1-D grid (n/128 * NHEADS * NSPLIT), block 512 = 8 waves x 16 q-rows.
// Head->XCD pinning: fid = h + 16*rest => fid%8 == h%8 (2 heads per XCD L2).
#define QB  128
#define KVB 64
#define NSPLIT 4
__global__ __launch_bounds__(512) void attn_part_kernel(
        const unsigned short* __restrict__ qb_,  // [H][n][128] (pre-scaled)
        const unsigned short* __restrict__ kb,   // [H][n][128]
        const unsigned short* __restrict__ vt,   // [H][128][n]
        unsigned short* __restrict__ o_part,     // [S][H][n][128] bf16
        float* __restrict__ m_part,              // [S][H][n]
        float* __restrict__ l_part, int n) {
    int nqb  = n / QB;                           // 16
    int fid  = blockIdx.x;
    int h    = fid & 15;                         // NHEADS-1
    int rest = fid >> 4;                         // 0 .. nqb*NSPLIT-1
    int qbi  = (nqb - 1) - (rest % nqb);         // long q-blocks first
    int s    = rest / nqb;
    int q0   = qbi * QB;
    int ntiles = (q0 + QB) / KVB;                // 2*(qbi+1)
    int chunk  = (ntiles + NSPLIT - 1) >> 2;
    int t0 = s * chunk;
    int t1 = t0 + chunk; if (t1 > ntiles) t1 = ntiles;
    int tid = threadIdx.x;

    if (t0 >= ntiles) {                          // empty split: weight-0 partial
        if (tid < QB) {
            size_t idx = ((size_t)s * NHEADS + h) * n + q0 + tid;
            m_part[idx] = NEGBIG;
            l_part[idx] = 0.f;
            for (int e = 0; e < HD / 8; ++e) {
                U16x8 z; z.v = make_uint4(0, 0, 0, 0);
                *(uint4*)&o_part[idx * HD + e * 8] = z.v;
            }
        }
        return;
    }

    int lane = tid & 63, w = tid >> 6;           // w = 0..7
    int g = lane >> 4, i = lane & 15;
    int myrow0 = q0 + w * 16;                    // wave's q-row base

    __shared__ __align__(16) unsigned short Kb[KVB][136];   // 17.4 KB
    __shared__ __align__(16) unsigned short Vt[128][72];    // 18.4 KB
    __shared__ __align__(16) unsigned short Pl[8][16][72];  // 18.4 KB

    bf16x8 qf[4];
    {
        const unsigned short* qrow = qb_ + ((size_t)h * n + myrow0 + i) * HD;
#pragma unroll
        for (int kk = 0; kk < 4; ++kk)
            qf[kk] = as_frag(*(const uint4*)&qrow[kk * 32 + 8 * g]);
    }

    f32x4 o_acc[8] = {};
    float m_r[4], l_r[4];
#pragma unroll
    for (int r = 0; r < 4; ++r) { m_r[r] = 0.f; l_r[r] = 0.f; }

    for (int kt = t0; kt < t1; ++kt) {
        int k0 = kt * KVB;
        // stage K tile: 64x128 = 1024 16B chunks (2 iters x 512 thr)
#pragma unroll
        for (int u = 0; u < 2; ++u) {
            int c = tid + u * 512;
            int row = c >> 4, col = (c & 15) * 8;
            *(uint4*)&Kb[row][col] =
                *(const uint4*)&kb[((size_t)h * n + k0 + row) * HD + col];
        }
        // stage V^T tile: 128x64 = 1024 16B chunks
#pragma unroll
        for (int u = 0; u < 2; ++u) {
            int c = tid + u * 512;
            int row = c >> 3, col = (c & 7) * 8;
            *(uint4*)&Vt[row][col] =
                *(const uint4*)&vt[((size_t)h * HD + row) * n + k0 + col];
        }
        __syncthreads();

        // QK^T
        f32x4 s_acc[4] = {};
#pragma unroll
        for (int nb = 0; nb < 4; ++nb)
#pragma unroll
            for (int kk = 0; kk < 4; ++kk) {
                bf16x8 kf = as_frag(*(const uint4*)&Kb[nb * 16 + i][kk * 32 + 8 * g]);
                s_acc[nb] = __builtin_amdgcn_mfma_f32_16x16x32_bf16(
                    qf[kk], kf, s_acc[nb], 0, 0, 0);
            }

        // causal mask: only the last two tiles of the q-block touch the diagonal
        bool diagzone = (kt >= ntiles - 2);
        float mx[4];
#pragma unroll
        for (int r = 0; r < 4; ++r) mx[r] = NEGBIG;
#pragma unroll
        for (int nb = 0; nb < 4; ++nb)
#pragma unroll
            for (int r = 0; r < 4; ++r) {
                float sv = s_acc[nb][r];
                if (diagzone && (k0 + nb * 16 + i > myrow0 + 4 * g + r)) sv = NEGBIG;
                s_acc[nb][r] = sv;
                mx[r] = fmaxf(mx[r], sv);
            }
#pragma unroll
        for (int off = 1; off < 16; off <<= 1)
#pragma unroll
            for (int r = 0; r < 4; ++r)
                mx[r] = fmaxf(mx[r], __shfl_xor(mx[r], off));

        float alpha[4], sum[4];
#pragma unroll
        for (int r = 0; r < 4; ++r) {
            float mnew = fmaxf(m_r[r], mx[r]);
            alpha[r] = __expf(m_r[r] - mnew);
            m_r[r] = mnew;
            sum[r] = 0.f;
        }
#pragma unroll
        for (int nb = 0; nb < 4; ++nb)
#pragma unroll
            for (int r = 0; r < 4; ++r) {
                float p = __expf(s_acc[nb][r] - m_r[r]);
                s_acc[nb][r] = p;
                sum[r] += p;
            }
#pragma unroll
        for (int off = 1; off < 16; off <<= 1)
#pragma unroll
            for (int r = 0; r < 4; ++r)
                sum[r] += __shfl_xor(sum[r], off);
#pragma unroll
        for (int r = 0; r < 4; ++r) l_r[r] = l_r[r] * alpha[r] + sum[r];

#pragma unroll
        for (int d0 = 0; d0 < 8; ++d0)
#pragma unroll
            for (int r = 0; r < 4; ++r)
                o_acc[d0][r] *= alpha[r];

#pragma unroll
        for (int nb = 0; nb < 4; ++nb)
#pragma unroll
            for (int r = 0; r < 4; ++r)
                Pl[w][4 * g + r][nb * 16 + i] = f2bf(s_acc[nb][r]);
        __builtin_amdgcn_sched_barrier(0);

        // PV from LDS
#pragma unroll
        for (int kk = 0; kk < 2; ++kk) {
            bf16x8 pf = as_frag(*(const uint4*)&Pl[w][i][kk * 32 + 8 * g]);
#pragma unroll
            for (int d0 = 0; d0 < 8; ++d0) {
                bf16x8 vf = as_frag(*(const uint4*)&Vt[d0 * 16 + i][kk * 32 + 8 * g]);
                o_acc[d0] = __builtin_amdgcn_mfma_f32_16x16x32_bf16(
                    pf, vf, o_acc[d0], 0, 0, 0);
            }
        }
        __syncthreads();
    }

    // epilogue: write unnormalized partials
#pragma unroll
    for (int r = 0; r < 4; ++r) {
        int q = myrow0 + 4 * g + r;
        size_t idx = ((size_t)s * NHEADS + h) * n + q;
#pragma unroll
        for (int d0 = 0; d0 < 8; ++d0)
            o_part[idx * HD + d0 * 16 + i] = f2bf(o_acc[d0][r]);
        if (i == 0) { m_part[idx] = m_r[r]; l_part[idx] = l_r[r]; }
    }
}

// ---------------- combine NSPLIT partials ----------------
__global__ __launch_bounds__(256) void attn_combine_kernel(
        const unsigned short* __restrict__ o_part,
        const float* __restrict__ m_part, const float* __restrict__ l_part,
        unsigned short* __restrict__ ob, int n) {
    int q = blockIdx.x;
    int t = threadIdx.x;
    int h = t >> 4;
    int d = (t & 15) * 8;

    float m[NSPLIT], mstar = NEGBIG;
#pragma unroll
    for (int s = 0; s < NSPLIT; ++s) {
        m[s] = m_part[((size_t)s * NHEADS + h) * n + q];
        mstar = fmaxf(mstar, m[s]);
    }
    float l = 0.f, o[8] = {};
#pragma unroll
    for (int s = 0; s < NSPLIT; ++s) {
        if (m[s] < -1e4f) continue;          // empty split: contributes nothing
        float ws = __expf(m[s] - mstar);
        l += ws * l_part[((size_t)s * NHEADS + h) * n + q];
        U16x8 ov;
        ov.v = *(const uint4*)&o_part[(((size_t)s * NHEADS + h) * n + q) * HD + d];
#pragma unroll
        for (int e = 0; e < 8; ++e) o[e] += ws * bf2f(ov.h[e]);
    }
    float inv = 1.f / l;
    U16x8 w8;
#pragma unroll
    for (int e = 0; e < 8; ++e) w8.h[e] = f2bf(o[e] * inv);
    *(uint4*)&ob[(size_t)q * HIDDEN + h * HD + d] = w8.v;
}

extern "C" void kernel_launch(void* const* d_in, const int* in_sizes, int n_in,
                              void* d_out, int out_size, void* d_ws, size_t ws_size,
                              hipStream_t stream) {
    const float* x     = (const float*)d_in[0];
    const float* nsc   = (const float*)d_in[1];
    const float* qkv_w = (const float*)d_in[2];
    const float* qkv_b = (const float*)d_in[3];
    const float* out_w = (const float*)d_in[4];
    const float* out_b = (const float*)d_in[5];
    float* out = (float*)d_out;
    int n = in_sizes[0] / HIDDEN;     // 2048

    // Workspace (~77 MB). Lifetimes:
    //   wq, tb, cost, sint dead after fused QKV GEMM ->
    //   o_part aliases wq+tb (exactly 32 MiB), m/l_part alias cost/sint.
    char* w = (char*)d_ws;
    unsigned short* wq = (unsigned short*)w;  w += (size_t)QKV3 * HIDDEN * 2;   // 25.2MB
    unsigned short* tb = (unsigned short*)w;  w += (size_t)2048 * HIDDEN * 2;   // 8.4MB (n=2048)
    unsigned short* wo = (unsigned short*)w;  w += (size_t)HIDDEN * HIDDEN * 2; // 8.4MB
    unsigned short* qb = (unsigned short*)w;  w += (size_t)n * HIDDEN * 2;
    unsigned short* kb = (unsigned short*)w;  w += (size_t)n * HIDDEN * 2;
    unsigned short* vt = (unsigned short*)w;  w += (size_t)n * HIDDEN * 2;
    float* cost = (float*)w;                  w += (size_t)n * 64 * 4;
    float* sint = (float*)w;                  w += (size_t)n * 64 * 4;
    unsigned short* ob = (unsigned short*)w;  w += (size_t)n * HIDDEN * 2;

    unsigned short* o_part = wq;                         // 4*16*n*128*2 = 32MiB = wq+tb
    float* m_part = cost;                                // 4*16*n*4 = 512KB = cost
    float* l_part = sint;                                // = sint

    int c1 = QKV3 * HIDDEN, c2 = HIDDEN * HIDDEN;
    int nconv = (c1 + c2) >> 10;
    prologue_kernel<<<nconv + (n >> 2) + n, 256, 0, stream>>>(
        qkv_w, wq, c1, out_w, wo, c2, cost, sint, x, nsc, tb, n);
    gemm_qkv_fused_kernel<<<dim3(QKV3 / 128, n / 128), 256, 0, stream>>>(
        tb, wq, qkv_b, cost, sint, qb, kb, vt, n);
    attn_part_kernel<<<dim3((n / QB) * NHEADS * NSPLIT), 512, 0, stream>>>(
        qb, kb, vt, o_part, m_part, l_part, n);
    attn_combine_kernel<<<n, 256, 0, stream>>>(o_part, m_part, l_part, ob, n);
    gemm_bf16_kernel<<<dim3(HIDDEN / 128, n / 128), 256, 0, stream>>>(
        ob, wo, out_b, x, out, n, HIDDEN, HIDDEN);
}